// Round 6
// baseline (129.754 us; speedup 1.0000x reference)
//
#include <hip/hip_runtime.h>
#include <hip/hip_bf16.h>

#define C_   32
#define K_   16
#define DLLM 768
#define DM   256
#define H_   8
#define DK   32
#define G_   256
#define BL   4096
#define NN   4096
#define E_   768
#define LDP  4160          // P / VWt row stride: 4096 + 32 bias-fold + 32 zero pad (65*64)
#define TEMPF 0.17677669529663687f
#define SCL2  0.2550348647f   // TEMP * log2(e): logits pre-scaled so epilogue is exp2

typedef __attribute__((ext_vector_type(8))) short bf16x8;
typedef __attribute__((ext_vector_type(4))) float f32x4;
typedef unsigned int u32;

__device__ __forceinline__ unsigned short f2bf(float f) {
    unsigned int u = __float_as_uint(f);
    unsigned int r = (u + 0x7fffu + ((u >> 16) & 1u)) >> 16;
    return (unsigned short)r;
}

// async global -> LDS, 16 bytes per lane (wave-uniform LDS base + lane*16)
__device__ __forceinline__ void gl16(const void* g, void* l) {
    __builtin_amdgcn_global_load_lds(
        (const __attribute__((address_space(1))) u32*)g,
        (__attribute__((address_space(3))) u32*)l, 16, 0, 0);
}

// ---------------------------------------------------------------- K1: kk,v partial projections (d-split x8)
__global__ __launch_bounds__(256) void k1_kv(const float* __restrict__ topk,
                                             const float* __restrict__ kp,
                                             const float* __restrict__ vp,
                                             float* __restrict__ partk,
                                             float* __restrict__ partv) {
    const int c  = blockIdx.x;          // 0..31
    const int dc = blockIdx.y;          // 0..7
    const int d0 = dc * 96;
    const int g  = threadIdx.x;         // 0..255
    __shared__ float t_l[K_][96];       // 6 KB
    for (int i = threadIdx.x; i < 384; i += 256) {
        int k = i / 24, c4 = (i % 24) * 4;
        *reinterpret_cast<float4*>(&t_l[k][c4]) =
            *reinterpret_cast<const float4*>(topk + (size_t)(c * K_ + k) * DLLM + d0 + c4);
    }
    __syncthreads();
    const float* kpr = kp + (size_t)(c * G_ + g) * (DLLM + 1) + d0;
    const float* vpr = vp + (size_t)(c * G_ + g) * (DLLM + 1) + d0;
    float acck[K_] = {}, accv[K_] = {};
    for (int d = 0; d < 96; d += 4) {
        float4 wk4 = *reinterpret_cast<const float4*>(kpr + d);
        float4 wv4 = *reinterpret_cast<const float4*>(vpr + d);
        const float wk[4] = {wk4.x, wk4.y, wk4.z, wk4.w};
        const float wv[4] = {wv4.x, wv4.y, wv4.z, wv4.w};
#pragma unroll
        for (int dd = 0; dd < 4; ++dd)
#pragma unroll
            for (int k = 0; k < K_; ++k) {
                acck[k] += wk[dd] * t_l[k][d + dd];
                accv[k] += wv[dd] * t_l[k][d + dd];
            }
    }
    float* pk = partk + ((size_t)(c * 8 + dc) * K_) * G_ + g;
    float* pv = partv + ((size_t)(c * 8 + dc) * K_) * G_ + g;
#pragma unroll
    for (int k = 0; k < K_; ++k) {
        pk[k * G_] = acck[k];
        pv[k * G_] = accv[k];
    }
}

// ---------------------------------------------------------------- K1r: kk/vv = sum partials + bias
__global__ __launch_bounds__(256) void k1r(const float* __restrict__ partk,
                                           const float* __restrict__ partv,
                                           const float* __restrict__ kp,
                                           const float* __restrict__ vp,
                                           float* __restrict__ kk,
                                           float* __restrict__ vv) {
    const int idx = blockIdx.x * 256 + threadIdx.x;   // (c*16+k)*256+g
    const int g = idx & 255, rest = idx >> 8;
    const int k = rest & 15, c = rest >> 4;
    float sk = kp[(size_t)(c * G_ + g) * (DLLM + 1) + DLLM];
    float sv = vp[(size_t)(c * G_ + g) * (DLLM + 1) + DLLM];
#pragma unroll
    for (int dc = 0; dc < 8; ++dc) {
        sk += partk[((size_t)(c * 8 + dc) * K_ + k) * G_ + g];
        sv += partv[((size_t)(c * 8 + dc) * K_ + k) * G_ + g];
    }
    kk[idx] = sk;
    vv[idx] = sv;
}

// ---------------------------------------------------------------- k0: ts->bf16 + bias-fold + zero-pad columns of P and VWt
__global__ __launch_bounds__(256) void k0_cvt(const float* __restrict__ ts,
                                              const float* __restrict__ probs,
                                              const float* __restrict__ outb,
                                              unsigned short* __restrict__ tsb,
                                              unsigned short* __restrict__ P,
                                              unsigned short* __restrict__ VWt) {
    const int bid = blockIdx.x, t = threadIdx.x;
    if (bid < 1024) {                              // ts (4096x256) -> bf16
        const int idx = bid * 1024 + t * 4;
        float4 v = *reinterpret_cast<const float4*>(ts + idx);
        uint2 o;
        o.x = f2bf(v.x) | ((unsigned)f2bf(v.y) << 16);
        o.y = f2bf(v.z) | ((unsigned)f2bf(v.w) << 16);
        *reinterpret_cast<uint2*>(tsb + idx) = o;
    } else if (bid < 1056) {                       // P[:,4096+c]=probs, P[:,4128..4159]=0
        const int b2 = bid - 1024;
        const int row = b2 * 128 + (t >> 1);
        const int ch = (t & 1) * 16;
        unsigned short o[16];
#pragma unroll
        for (int j = 0; j < 16; ++j) o[j] = f2bf(probs[row * 32 + ch + j]);
        uint4 u0, u1;
        u0.x = o[0] | (o[1] << 16);  u0.y = o[2] | (o[3] << 16);
        u0.z = o[4] | (o[5] << 16);  u0.w = o[6] | (o[7] << 16);
        u1.x = o[8] | (o[9] << 16);  u1.y = o[10] | (o[11] << 16);
        u1.z = o[12] | (o[13] << 16); u1.w = o[14] | (o[15] << 16);
        unsigned short* dst = P + (size_t)row * LDP + 4096 + ch;
        *reinterpret_cast<uint4*>(dst) = u0;
        *reinterpret_cast<uint4*>(dst + 8) = u1;
        uint4 z = {0u, 0u, 0u, 0u};
        unsigned short* pz = P + (size_t)row * LDP + 4128 + ch;
        *reinterpret_cast<uint4*>(pz) = z;
        *reinterpret_cast<uint4*>(pz + 8) = z;
    } else {                                       // VWt[e][4096+c]=outb[c][e]; pad=0
        const int idx = (bid - 1056) * 256 + t;    // 768*32 = 24576
        const int e = idx >> 5, cc = idx & 31;
        VWt[(size_t)e * LDP + 4096 + cc] = f2bf(outb[cc * E_ + e]);
        VWt[(size_t)e * LDP + 4128 + cc] = 0;
    }
}

// ---------------------------------------------------------------- K2: A2t[n][m] bf16 (pre-scaled), abias[n] fp32 (pre-scaled)
__global__ __launch_bounds__(256) void k2_A(const float* __restrict__ qp,
                                            const float* __restrict__ kk,
                                            unsigned short* __restrict__ A2t,
                                            float* __restrict__ abias) {
    const int c = blockIdx.x, h = blockIdx.y;
    const int m = threadIdx.x;
    __shared__ float kk_l[K_][DK];
    __shared__ float bq_l[DK];
    for (int i = threadIdx.x; i < K_ * DK; i += 256) {
        int k = i / DK, d = i % DK;
        kk_l[k][d] = kk[(size_t)(c * K_ + k) * G_ + h * DK + d];
    }
    if (threadIdx.x < DK)
        bq_l[threadIdx.x] = qp[(size_t)(c * G_ + h * DK + threadIdx.x) * (DM + 1) + DM];
    __syncthreads();
    float acc[K_];
#pragma unroll
    for (int k = 0; k < K_; ++k) acc[k] = 0.f;
    for (int d = 0; d < DK; ++d) {
        float wq = qp[(size_t)(c * G_ + h * DK + d) * (DM + 1) + m];
#pragma unroll
        for (int k = 0; k < K_; ++k) acc[k] += wq * kk_l[k][d];
    }
    const int ch = c * H_ + h;
#pragma unroll
    for (int k = 0; k < K_; ++k)
        A2t[(size_t)(ch * 16 + k) * DM + m] = f2bf(acc[k] * SCL2);
    if (m < K_) {
        float s = 0.f;
#pragma unroll
        for (int d = 0; d < DK; ++d) s += bq_l[d] * kk_l[m][d];
        abias[ch * 16 + m] = s * SCL2;
    }
}

// ---------------------------------------------------------------- K3: VWt[e][n] bf16
__global__ __launch_bounds__(768) void k3_VW(const float* __restrict__ ow,
                                             const float* __restrict__ vv,
                                             unsigned short* __restrict__ VWt) {
    const int c = blockIdx.x, h = blockIdx.y;
    const int e = threadIdx.x;
    __shared__ float v_l[K_][DK];
    for (int i = threadIdx.x; i < K_ * DK; i += 768) {
        int k = i / DK, d = i % DK;
        v_l[k][d] = vv[(size_t)(c * K_ + k) * G_ + h * DK + d];
    }
    __syncthreads();
    float acc[K_];
#pragma unroll
    for (int k = 0; k < K_; ++k) acc[k] = 0.f;
    for (int d = 0; d < DK; ++d) {
        float w = ow[((size_t)(c * H_ + h) * DK + d) * E_ + e];
#pragma unroll
        for (int k = 0; k < K_; ++k) acc[k] += w * v_l[k][d];
    }
    const int ch = c * H_ + h;
#pragma unroll
    for (int k = 0; k < K_; ++k)
        VWt[(size_t)e * LDP + ch * 16 + k] = f2bf(acc[k]);
}

// ---------------------------------------------------------------- K4: MFMA logits + exp2-softmax + prob scale -> P bf16
// D[n][bl] = A2t[n][m].tsb[bl][m]; 128x128 tile, BK=32, gload_lds dbuf, 4-chunk XOR swizzle
__global__ __launch_bounds__(256) void k4_att(const unsigned short* __restrict__ A2t,
                                              const unsigned short* __restrict__ tsb,
                                              const float* __restrict__ abias,
                                              const float* __restrict__ probs,
                                              unsigned short* __restrict__ P) {
    const int n0  = blockIdx.x * 128;
    const int bl0 = blockIdx.y * 128;
    const int t = threadIdx.x;
    const int lane = t & 63, w = t >> 6;
    const int wr = w >> 1, wc = w & 1;
    const int c = lane & 15, g = lane >> 4;
    const int c3 = c & 3;

    __shared__ unsigned short a_l[2][128 * 32];
    __shared__ unsigned short b_l[2][128 * 32];
    __shared__ float ab_l[128];
    __shared__ float pb_l[128];

    if (t < 128) {
        ab_l[t] = abias[n0 + t];
        pb_l[t] = probs[(size_t)(bl0 + t) * C_ + (n0 >> 7)];
    }

    // staging: 16B/lane; row = (w*2+j)*16 + (lane>>2); source chunk XOR'd by row&3
    const int srow = lane >> 2;
    const int soff = (((lane & 3) ^ (srow & 3))) * 8;   // swizzled 16B chunk (shorts)

    f32x4 acc[4][4] = {};

#pragma unroll
    for (int j = 0; j < 2; ++j) {
        const int r = (w * 2 + j) * 16 + srow;
        gl16(A2t + (size_t)(n0 + r) * DM + soff,  &a_l[0][(w * 2 + j) * 512 + lane * 8]);
        gl16(tsb + (size_t)(bl0 + r) * DM + soff, &b_l[0][(w * 2 + j) * 512 + lane * 8]);
    }
    __syncthreads();

    for (int kt = 0; kt < 8; ++kt) {
        const int cur = kt & 1;
        if (kt < 7) {
#pragma unroll
            for (int j = 0; j < 2; ++j) {
                const int r = (w * 2 + j) * 16 + srow;
                gl16(A2t + (size_t)(n0 + r) * DM + (kt + 1) * 32 + soff,
                     &a_l[cur ^ 1][(w * 2 + j) * 512 + lane * 8]);
                gl16(tsb + (size_t)(bl0 + r) * DM + (kt + 1) * 32 + soff,
                     &b_l[cur ^ 1][(w * 2 + j) * 512 + lane * 8]);
            }
        }
        bf16x8 af[4], bfr[4];
#pragma unroll
        for (int a = 0; a < 4; ++a)
            af[a] = *reinterpret_cast<const bf16x8*>(
                &a_l[cur][(wr * 64 + a * 16 + c) * 32 + ((g ^ c3)) * 8]);
#pragma unroll
        for (int b = 0; b < 4; ++b)
            bfr[b] = *reinterpret_cast<const bf16x8*>(
                &b_l[cur][(wc * 64 + b * 16 + c) * 32 + ((g ^ c3)) * 8]);
#pragma unroll
        for (int a = 0; a < 4; ++a)
#pragma unroll
            for (int b = 0; b < 4; ++b)
                acc[a][b] = __builtin_amdgcn_mfma_f32_16x16x32_bf16(af[a], bfr[b], acc[a][b], 0, 0, 0);
        __syncthreads();
    }

    // epilogue: logits pre-scaled by TEMP*log2e -> exp2; no max-sub (|z| ~< 2); rcp; cvt_pk
#pragma unroll
    for (int a = 0; a < 4; ++a) {
        const int nbase = wr * 64 + a * 16 + g * 4;
#pragma unroll
        for (int b = 0; b < 4; ++b) {
            const int bll = wc * 64 + b * 16 + c;
            float e0 = __builtin_amdgcn_exp2f(acc[a][b][0] + ab_l[nbase + 0]);
            float e1 = __builtin_amdgcn_exp2f(acc[a][b][1] + ab_l[nbase + 1]);
            float e2 = __builtin_amdgcn_exp2f(acc[a][b][2] + ab_l[nbase + 2]);
            float e3 = __builtin_amdgcn_exp2f(acc[a][b][3] + ab_l[nbase + 3]);
            float s = (e0 + e1) + (e2 + e3);
            s += __shfl_xor(s, 16);
            s += __shfl_xor(s, 32);
            const float pv = pb_l[bll] * __builtin_amdgcn_rcpf(s);
            unsigned r0, r1;
            float p0 = e0 * pv, p1 = e1 * pv, p2 = e2 * pv, p3 = e3 * pv;
            asm("v_cvt_pk_bf16_f32 %0, %1, %2" : "=v"(r0) : "v"(p0), "v"(p1));
            asm("v_cvt_pk_bf16_f32 %0, %1, %2" : "=v"(r1) : "v"(p2), "v"(p3));
            uint2 o; o.x = r0; o.y = r1;
            *reinterpret_cast<uint2*>(P + (size_t)(bl0 + bll) * LDP + n0 + nbase) = o;
        }
    }
}

// ---------------------------------------------------------------- K5: part[ks] = P(K-half) @ VWt^T
// BM=64, BN=96, BK=64, split-K=2 (2048 | 2112 incl. bias-fold); 8-chunk XOR swizzle;
// XCD swizzle: each XCD owns one e-column (VWt slice L2-resident), both K-halves local.
__global__ __launch_bounds__(256) void k5_out(const unsigned short* __restrict__ P,
                                              const unsigned short* __restrict__ VWt,
                                              float* __restrict__ part) {
    const int wg = blockIdx.x;                       // 0..1023
    const int nl = (wg & 7) * 128 + (wg >> 3);       // XCD-chunked
    const int e0  = (nl >> 7) * 96;                  // 0..7 -> e column
    const int idx = nl & 127;
    const int bl0 = (idx & 63) * 64;
    const int ks  = idx >> 6;                        // 0 or 1

    const int t = threadIdx.x;
    const int lane = t & 63, w = t >> 6;
    const int wr = w >> 1, wc = w & 1;
    const int c = lane & 15, g = lane >> 4;
    const int c7 = c & 7;

    __shared__ unsigned short a_l[2][64 * 64];       // 8 KB each buf
    __shared__ unsigned short b_l[2][96 * 64];       // 12 KB each buf

    const int nstart = ks * 2048;
    const int nsteps = 32 + ks;                      // ks1 covers bias-fold + zero pad

    // staging: row = j*32 + w*8 + (lane>>3); src 16B chunk = (lane&7) ^ (row&7)
    const int rsub = lane >> 3;
    const int csrc = (((lane & 7) ^ (rsub & 7))) * 8;

    // prologue: tile 0 -> buf 0
#pragma unroll
    for (int j = 0; j < 2; ++j)
        gl16(P + (size_t)(bl0 + j * 32 + w * 8 + rsub) * LDP + nstart + csrc,
             &a_l[0][j * 2048 + w * 512 + lane * 8]);
#pragma unroll
    for (int j = 0; j < 3; ++j)
        gl16(VWt + (size_t)(e0 + j * 32 + w * 8 + rsub) * LDP + nstart + csrc,
             &b_l[0][j * 2048 + w * 512 + lane * 8]);
    __syncthreads();

    f32x4 acc[2][3] = {};
    for (int kt = 0; kt < nsteps; ++kt) {
        const int cur = kt & 1;
        if (kt + 1 < nsteps) {
            const int col = nstart + (kt + 1) * 64 + csrc;
#pragma unroll
            for (int j = 0; j < 2; ++j)
                gl16(P + (size_t)(bl0 + j * 32 + w * 8 + rsub) * LDP + col,
                     &a_l[cur ^ 1][j * 2048 + w * 512 + lane * 8]);
#pragma unroll
            for (int j = 0; j < 3; ++j)
                gl16(VWt + (size_t)(e0 + j * 32 + w * 8 + rsub) * LDP + col,
                     &b_l[cur ^ 1][j * 2048 + w * 512 + lane * 8]);
        }
#pragma unroll
        for (int ks2 = 0; ks2 < 2; ++ks2) {
            bf16x8 af[2], bfr[3];
#pragma unroll
            for (int a = 0; a < 2; ++a)
                af[a] = *reinterpret_cast<const bf16x8*>(
                    &a_l[cur][(wr * 32 + a * 16 + c) * 64 + (((ks2 * 4 + g) ^ c7)) * 8]);
#pragma unroll
            for (int b = 0; b < 3; ++b)
                bfr[b] = *reinterpret_cast<const bf16x8*>(
                    &b_l[cur][(wc * 48 + b * 16 + c) * 64 + (((ks2 * 4 + g) ^ c7)) * 8]);
#pragma unroll
            for (int a = 0; a < 2; ++a)
#pragma unroll
                for (int b = 0; b < 3; ++b)
                    acc[a][b] = __builtin_amdgcn_mfma_f32_16x16x32_bf16(af[a], bfr[b], acc[a][b], 0, 0, 0);
        }
        __syncthreads();
    }

    float* pp = part + ((size_t)ks * BL + bl0) * E_ + e0;
#pragma unroll
    for (int a = 0; a < 2; ++a)
#pragma unroll
        for (int b = 0; b < 3; ++b)
#pragma unroll
            for (int i = 0; i < 4; ++i)
                pp[(size_t)(wr * 32 + a * 16 + g * 4 + i) * E_ + wc * 48 + b * 16 + c] = acc[a][b][i];
}

// ---------------------------------------------------------------- k6: out = part0 + part1
__global__ __launch_bounds__(256) void k6_red(const float* __restrict__ part,
                                              float* __restrict__ out) {
    const int idx = (blockIdx.x * 256 + threadIdx.x) * 4;
    float4 p0 = *reinterpret_cast<const float4*>(part + idx);
    float4 p1 = *reinterpret_cast<const float4*>(part + (size_t)BL * E_ + idx);
    float4 o = make_float4(p0.x + p1.x, p0.y + p1.y, p0.z + p1.z, p0.w + p1.w);
    *reinterpret_cast<float4*>(out + idx) = o;
}

// ----------------------------------------------------------------
extern "C" void kernel_launch(void* const* d_in, const int* in_sizes, int n_in,
                              void* d_out, int out_size, void* d_ws, size_t ws_size,
                              hipStream_t stream) {
    const float* topk  = (const float*)d_in[0];
    const float* ts    = (const float*)d_in[1];
    const float* probs = (const float*)d_in[2];
    const float* qp    = (const float*)d_in[3];
    const float* kp    = (const float*)d_in[4];
    const float* vp    = (const float*)d_in[5];
    const float* ow    = (const float*)d_in[6];
    const float* ob    = (const float*)d_in[7];
    float* out = (float*)d_out;

    char* wp = (char*)d_ws;
    float* kk            = (float*)wp;           wp += 524288;
    float* vv            = (float*)wp;           wp += 524288;
    float* ab            = (float*)wp;           wp += 16384;
    unsigned short* tsb  = (unsigned short*)wp;  wp += 2097152;
    unsigned short* A2t  = (unsigned short*)wp;  wp += 2097152;
    unsigned short* VWt  = (unsigned short*)wp;  wp += (size_t)E_ * LDP * 2;   // 6,389,760
    unsigned short* P    = (unsigned short*)wp;  wp += (size_t)BL * LDP * 2;   // 34,078,720
    float* partk         = (float*)wp;           wp += 4194304;
    float* partv         = (float*)wp;           wp += 4194304;
    float* part          = (float*)wp;           // 2 * 4096*768*4 = 25,165,824

    k1_kv <<<dim3(32, 8),  256, 0, stream>>>(topk, kp, vp, partk, partv);
    k1r   <<<512,          256, 0, stream>>>(partk, partv, kp, vp, kk, vv);
    k0_cvt<<<1152,         256, 0, stream>>>(ts, probs, ob, tsb, P, VWt);
    k2_A  <<<dim3(32, 8),  256, 0, stream>>>(qp, kk, A2t, ab);
    k3_VW <<<dim3(32, 8),  768, 0, stream>>>(ow, vv, VWt);
    k4_att<<<dim3(32, 32), 256, 0, stream>>>(A2t, tsb, ab, probs, P);
    k5_out<<<1024,         256, 0, stream>>>(P, VWt, part);
    k6_red<<<3072,         256, 0, stream>>>(part, out);
}

// Round 7
// 122.526 us; speedup vs baseline: 1.0590x; 1.0590x over previous
//
#include <hip/hip_runtime.h>
#include <hip/hip_bf16.h>

#define C_   32
#define K_   16
#define DLLM 768
#define DM   256
#define H_   8
#define DK   32
#define G_   256
#define BL   4096
#define NN   4096
#define E_   768
#define LDP  4160          // P / VWt row stride: 4096 + 32 bias-fold + 32 zero pad
#define TEMPF 0.17677669529663687f
#define SCL2  0.2550348647f   // TEMP * log2(e)

typedef __attribute__((ext_vector_type(8))) short bf16x8;
typedef __attribute__((ext_vector_type(4))) float f32x4;
typedef unsigned int u32;

__device__ __forceinline__ unsigned short f2bf(float f) {
    unsigned int u = __float_as_uint(f);
    unsigned int r = (u + 0x7fffu + ((u >> 16) & 1u)) >> 16;
    return (unsigned short)r;
}
__device__ __forceinline__ float bf2f(unsigned int u) {
    return __uint_as_float(u << 16);
}

// async global -> LDS, 16 bytes per lane (wave-uniform LDS base + lane*16)
__device__ __forceinline__ void gl16(const void* g, void* l) {
    __builtin_amdgcn_global_load_lds(
        (const __attribute__((address_space(1))) u32*)g,
        (__attribute__((address_space(3))) u32*)l, 16, 0, 0);
}

// ---------------------------------------------------------------- K1: kk,v partial projections (d-split x8)
__global__ __launch_bounds__(256) void k1_kv(const float* __restrict__ topk,
                                             const float* __restrict__ kp,
                                             const float* __restrict__ vp,
                                             float* __restrict__ partk,
                                             float* __restrict__ partv) {
    const int c  = blockIdx.x;
    const int dc = blockIdx.y;
    const int d0 = dc * 96;
    const int g  = threadIdx.x;
    __shared__ float t_l[K_][96];
    for (int i = threadIdx.x; i < 384; i += 256) {
        int k = i / 24, c4 = (i % 24) * 4;
        *reinterpret_cast<float4*>(&t_l[k][c4]) =
            *reinterpret_cast<const float4*>(topk + (size_t)(c * K_ + k) * DLLM + d0 + c4);
    }
    __syncthreads();
    const float* kpr = kp + (size_t)(c * G_ + g) * (DLLM + 1) + d0;
    const float* vpr = vp + (size_t)(c * G_ + g) * (DLLM + 1) + d0;
    float acck[K_] = {}, accv[K_] = {};
    for (int d = 0; d < 96; d += 4) {
        float4 wk4 = *reinterpret_cast<const float4*>(kpr + d);
        float4 wv4 = *reinterpret_cast<const float4*>(vpr + d);
        const float wk[4] = {wk4.x, wk4.y, wk4.z, wk4.w};
        const float wv[4] = {wv4.x, wv4.y, wv4.z, wv4.w};
#pragma unroll
        for (int dd = 0; dd < 4; ++dd)
#pragma unroll
            for (int k = 0; k < K_; ++k) {
                acck[k] += wk[dd] * t_l[k][d + dd];
                accv[k] += wv[dd] * t_l[k][d + dd];
            }
    }
    float* pk = partk + ((size_t)(c * 8 + dc) * K_) * G_ + g;
    float* pv = partv + ((size_t)(c * 8 + dc) * K_) * G_ + g;
#pragma unroll
    for (int k = 0; k < K_; ++k) {
        pk[k * G_] = acck[k];
        pv[k * G_] = accv[k];
    }
}

// ---------------------------------------------------------------- K1r0: (merged) k1-reduce + cvt/bias-fold
__global__ __launch_bounds__(256) void k1r0(const float* __restrict__ partk,
                                            const float* __restrict__ partv,
                                            const float* __restrict__ kp,
                                            const float* __restrict__ vp,
                                            float* __restrict__ kk,
                                            float* __restrict__ vv,
                                            const float* __restrict__ ts,
                                            const float* __restrict__ probs,
                                            const float* __restrict__ outb,
                                            unsigned short* __restrict__ tsb,
                                            unsigned short* __restrict__ P,
                                            unsigned short* __restrict__ VWt) {
    const int bid0 = blockIdx.x, t = threadIdx.x;
    if (bid0 < 512) {                              // k1r: kk/vv = sum partials + bias
        const int idx = bid0 * 256 + t;
        const int g = idx & 255, rest = idx >> 8;
        const int k = rest & 15, c = rest >> 4;
        float sk = kp[(size_t)(c * G_ + g) * (DLLM + 1) + DLLM];
        float sv = vp[(size_t)(c * G_ + g) * (DLLM + 1) + DLLM];
#pragma unroll
        for (int dc = 0; dc < 8; ++dc) {
            sk += partk[((size_t)(c * 8 + dc) * K_ + k) * G_ + g];
            sv += partv[((size_t)(c * 8 + dc) * K_ + k) * G_ + g];
        }
        kk[idx] = sk;
        vv[idx] = sv;
        return;
    }
    const int bid = bid0 - 512;
    if (bid < 1024) {                              // ts (4096x256) -> bf16
        const int idx = bid * 1024 + t * 4;
        float4 v = *reinterpret_cast<const float4*>(ts + idx);
        uint2 o;
        o.x = f2bf(v.x) | ((unsigned)f2bf(v.y) << 16);
        o.y = f2bf(v.z) | ((unsigned)f2bf(v.w) << 16);
        *reinterpret_cast<uint2*>(tsb + idx) = o;
    } else if (bid < 1056) {                       // P[:,4096+c]=probs, P[:,4128..4159]=0
        const int b2 = bid - 1024;
        const int row = b2 * 128 + (t >> 1);
        const int ch = (t & 1) * 16;
        unsigned short o[16];
#pragma unroll
        for (int j = 0; j < 16; ++j) o[j] = f2bf(probs[row * 32 + ch + j]);
        uint4 u0, u1;
        u0.x = o[0] | (o[1] << 16);  u0.y = o[2] | (o[3] << 16);
        u0.z = o[4] | (o[5] << 16);  u0.w = o[6] | (o[7] << 16);
        u1.x = o[8] | (o[9] << 16);  u1.y = o[10] | (o[11] << 16);
        u1.z = o[12] | (o[13] << 16); u1.w = o[14] | (o[15] << 16);
        unsigned short* dst = P + (size_t)row * LDP + 4096 + ch;
        *reinterpret_cast<uint4*>(dst) = u0;
        *reinterpret_cast<uint4*>(dst + 8) = u1;
        uint4 z = {0u, 0u, 0u, 0u};
        unsigned short* pz = P + (size_t)row * LDP + 4128 + ch;
        *reinterpret_cast<uint4*>(pz) = z;
        *reinterpret_cast<uint4*>(pz + 8) = z;
    } else {                                       // VWt[e][4096+c]=outb[c][e]; pad=0
        const int idx = (bid - 1056) * 256 + t;    // 768*32 = 24576
        const int e = idx >> 5, cc = idx & 31;
        VWt[(size_t)e * LDP + 4096 + cc] = f2bf(outb[cc * E_ + e]);
        VWt[(size_t)e * LDP + 4128 + cc] = 0;
    }
}

// ---------------------------------------------------------------- K23: (merged) A2t + VWt builders
__global__ __launch_bounds__(768) void k23(const float* __restrict__ qp,
                                           const float* __restrict__ kk,
                                           const float* __restrict__ ow,
                                           const float* __restrict__ vv,
                                           unsigned short* __restrict__ A2t,
                                           float* __restrict__ abias,
                                           unsigned short* __restrict__ VWt) {
    const int c = blockIdx.x, h = blockIdx.y;
    const int t = threadIdx.x;
    __shared__ float kk_l[K_][DK];
    __shared__ float v_l[K_][DK];
    __shared__ float bq_l[DK];
    if (t < 512) {
        int k = t / DK, d = t % DK;
        kk_l[k][d] = kk[(size_t)(c * K_ + k) * G_ + h * DK + d];
        v_l[k][d]  = vv[(size_t)(c * K_ + k) * G_ + h * DK + d];
    }
    if (t < DK)
        bq_l[t] = qp[(size_t)(c * G_ + h * DK + t) * (DM + 1) + DM];
    __syncthreads();
    const int ch = c * H_ + h;
    {   // k3: VWt[e][n]
        const int e = t;
        float acc[K_];
#pragma unroll
        for (int k = 0; k < K_; ++k) acc[k] = 0.f;
        for (int d = 0; d < DK; ++d) {
            float w = ow[((size_t)ch * DK + d) * E_ + e];
#pragma unroll
            for (int k = 0; k < K_; ++k) acc[k] += w * v_l[k][d];
        }
#pragma unroll
        for (int k = 0; k < K_; ++k)
            VWt[(size_t)e * LDP + ch * 16 + k] = f2bf(acc[k]);
    }
    if (t < 256) {  // k2: A2t[n][m] (pre-scaled), abias
        const int m = t;
        float acc[K_];
#pragma unroll
        for (int k = 0; k < K_; ++k) acc[k] = 0.f;
        for (int d = 0; d < DK; ++d) {
            float wq = qp[(size_t)(c * G_ + h * DK + d) * (DM + 1) + m];
#pragma unroll
            for (int k = 0; k < K_; ++k) acc[k] += wq * kk_l[k][d];
        }
#pragma unroll
        for (int k = 0; k < K_; ++k)
            A2t[(size_t)(ch * 16 + k) * DM + m] = f2bf(acc[k] * SCL2);
        if (m < K_) {
            float s = 0.f;
#pragma unroll
            for (int d = 0; d < DK; ++d) s += bq_l[d] * kk_l[m][d];
            abias[ch * 16 + m] = s * SCL2;
        }
    }
}

// ---------------------------------------------------------------- K4: MFMA logits + exp2-softmax + prob scale -> P bf16
// 128x128 tile, BK=32, gload_lds dbuf; conflict-free (r>>1)&3 swizzle (2-way max)
__global__ __launch_bounds__(256, 4) void k4_att(const unsigned short* __restrict__ A2t,
                                                 const unsigned short* __restrict__ tsb,
                                                 const float* __restrict__ abias,
                                                 const float* __restrict__ probs,
                                                 unsigned short* __restrict__ P) {
    const int n0  = blockIdx.x * 128;
    const int bl0 = blockIdx.y * 128;
    const int t = threadIdx.x;
    const int lane = t & 63, w = t >> 6;
    const int wr = w >> 1, wc = w & 1;
    const int c = lane & 15, g = lane >> 4;
    const int rsl = (c >> 1) & 3;                  // reader chunk swizzle

    __shared__ unsigned short a_l[2][128 * 32];
    __shared__ unsigned short b_l[2][128 * 32];
    __shared__ float ab_l[128];
    __shared__ float pb_l[128];

    if (t < 128) {
        ab_l[t] = abias[n0 + t];
        pb_l[t] = probs[(size_t)(bl0 + t) * C_ + (n0 >> 7)];
    }

    // staging: 4 lanes/row; LDS dest linear; source chunk pre-swizzled by (row>>1)&3
    const int srow = lane >> 2;
    const int sw = ((lane & 3) ^ ((lane >> 3) & 3)) * 8;

    f32x4 acc[4][4] = {};

#pragma unroll
    for (int j = 0; j < 2; ++j) {
        const int r = (w * 2 + j) * 16 + srow;
        gl16(A2t + (size_t)(n0 + r) * DM + sw,  &a_l[0][(w * 2 + j) * 512 + lane * 8]);
        gl16(tsb + (size_t)(bl0 + r) * DM + sw, &b_l[0][(w * 2 + j) * 512 + lane * 8]);
    }
    __syncthreads();

    for (int kt = 0; kt < 8; ++kt) {
        const int cur = kt & 1;
        if (kt < 7) {
#pragma unroll
            for (int j = 0; j < 2; ++j) {
                const int r = (w * 2 + j) * 16 + srow;
                gl16(A2t + (size_t)(n0 + r) * DM + (kt + 1) * 32 + sw,
                     &a_l[cur ^ 1][(w * 2 + j) * 512 + lane * 8]);
                gl16(tsb + (size_t)(bl0 + r) * DM + (kt + 1) * 32 + sw,
                     &b_l[cur ^ 1][(w * 2 + j) * 512 + lane * 8]);
            }
        }
        bf16x8 af[4], bfr[4];
#pragma unroll
        for (int a = 0; a < 4; ++a)
            af[a] = *reinterpret_cast<const bf16x8*>(
                &a_l[cur][(wr * 64 + a * 16 + c) * 32 + (g ^ rsl) * 8]);
#pragma unroll
        for (int b = 0; b < 4; ++b)
            bfr[b] = *reinterpret_cast<const bf16x8*>(
                &b_l[cur][(wc * 64 + b * 16 + c) * 32 + (g ^ rsl) * 8]);
#pragma unroll
        for (int a = 0; a < 4; ++a)
#pragma unroll
            for (int b = 0; b < 4; ++b)
                acc[a][b] = __builtin_amdgcn_mfma_f32_16x16x32_bf16(af[a], bfr[b], acc[a][b], 0, 0, 0);
        __syncthreads();
    }

#pragma unroll
    for (int a = 0; a < 4; ++a) {
        const int nbase = wr * 64 + a * 16 + g * 4;
#pragma unroll
        for (int b = 0; b < 4; ++b) {
            const int bll = wc * 64 + b * 16 + c;
            float e0 = __builtin_amdgcn_exp2f(acc[a][b][0] + ab_l[nbase + 0]);
            float e1 = __builtin_amdgcn_exp2f(acc[a][b][1] + ab_l[nbase + 1]);
            float e2 = __builtin_amdgcn_exp2f(acc[a][b][2] + ab_l[nbase + 2]);
            float e3 = __builtin_amdgcn_exp2f(acc[a][b][3] + ab_l[nbase + 3]);
            float s = (e0 + e1) + (e2 + e3);
            s += __shfl_xor(s, 16);
            s += __shfl_xor(s, 32);
            const float pv = pb_l[bll] * __builtin_amdgcn_rcpf(s);
            unsigned r0, r1;
            float p0 = e0 * pv, p1 = e1 * pv, p2 = e2 * pv, p3 = e3 * pv;
            asm("v_cvt_pk_bf16_f32 %0, %1, %2" : "=v"(r0) : "v"(p0), "v"(p1));
            asm("v_cvt_pk_bf16_f32 %0, %1, %2" : "=v"(r1) : "v"(p2), "v"(p3));
            uint2 o; o.x = r0; o.y = r1;
            *reinterpret_cast<uint2*>(P + (size_t)(bl0 + bll) * LDP + n0 + nbase) = o;
        }
    }
}

// ---------------------------------------------------------------- K5: part[ks] = P(K-quarter) @ VWt^T  (bf16 partials)
// BM=64, BN=192, BK=32, split-K=4 (1024/1024/1024/1088); conflict-free swizzle;
// XCD owns a bl-slice: P fetched ~once per slice; 1024 blocks = 4/CU.
__global__ __launch_bounds__(256, 4) void k5_out(const unsigned short* __restrict__ P,
                                                 const unsigned short* __restrict__ VWt,
                                                 unsigned short* __restrict__ part) {
    const int wg = blockIdx.x;                     // 0..1023
    const int xcd = wg & 7;
    const int local = wg >> 3;                     // 0..127
    const int bl0 = (xcd * 8 + (local & 7)) * 64;
    const int e0  = ((local >> 3) & 3) * 192;
    const int ks  = local >> 5;                    // 0..3

    const int t = threadIdx.x;
    const int lane = t & 63, w = t >> 6;
    const int wr = w >> 1, wc = w & 1;
    const int c = lane & 15, g = lane >> 4;
    const int rsl = (c >> 1) & 3;

    __shared__ unsigned short a_l[2][64 * 32];     // 4 KB / buf
    __shared__ unsigned short b_l[2][192 * 32];    // 12 KB / buf

    const int nstart = ks * 1024;
    const int nsteps = (ks == 3) ? 34 : 32;

    // staging: 4 lanes/row, linear dest, source chunk swizzled by (row>>1)&3
    const int srow = t >> 2;                       // A row / B row-within-64
    const int sw = ((t & 3) ^ ((t >> 3) & 3)) * 8;

    // prologue
    gl16(P + (size_t)(bl0 + srow) * LDP + nstart + sw, &a_l[0][t * 8]);
#pragma unroll
    for (int j = 0; j < 3; ++j)
        gl16(VWt + (size_t)(e0 + j * 64 + srow) * LDP + nstart + sw,
             &b_l[0][j * 2048 + t * 8]);
    __syncthreads();

    f32x4 acc[2][6] = {};
    for (int kt = 0; kt < nsteps; ++kt) {
        const int cur = kt & 1;
        if (kt + 1 < nsteps) {
            const int col = nstart + (kt + 1) * 32 + sw;
            gl16(P + (size_t)(bl0 + srow) * LDP + col, &a_l[cur ^ 1][t * 8]);
#pragma unroll
            for (int j = 0; j < 3; ++j)
                gl16(VWt + (size_t)(e0 + j * 64 + srow) * LDP + col,
                     &b_l[cur ^ 1][j * 2048 + t * 8]);
        }
        bf16x8 af[2], bfr[6];
#pragma unroll
        for (int a = 0; a < 2; ++a)
            af[a] = *reinterpret_cast<const bf16x8*>(
                &a_l[cur][(wr * 32 + a * 16 + c) * 32 + (g ^ rsl) * 8]);
#pragma unroll
        for (int b = 0; b < 6; ++b)
            bfr[b] = *reinterpret_cast<const bf16x8*>(
                &b_l[cur][(wc * 96 + b * 16 + c) * 32 + (g ^ rsl) * 8]);
#pragma unroll
        for (int a = 0; a < 2; ++a)
#pragma unroll
            for (int b = 0; b < 6; ++b)
                acc[a][b] = __builtin_amdgcn_mfma_f32_16x16x32_bf16(af[a], bfr[b], acc[a][b], 0, 0, 0);
        __syncthreads();
    }

    unsigned short* pp = part + ((size_t)ks * BL + bl0) * E_ + e0;
#pragma unroll
    for (int a = 0; a < 2; ++a)
#pragma unroll
        for (int b = 0; b < 6; ++b)
#pragma unroll
            for (int i = 0; i < 4; ++i)
                pp[(size_t)(wr * 32 + a * 16 + g * 4 + i) * E_ + wc * 96 + b * 16 + c] =
                    f2bf(acc[a][b][i]);
}

// ---------------------------------------------------------------- k6: out = sum of 4 bf16 partials
__global__ __launch_bounds__(256) void k6_red(const unsigned short* __restrict__ part,
                                              float* __restrict__ out) {
    const size_t base = ((size_t)blockIdx.x * 256 + threadIdx.x) * 8;
    float s[8] = {};
#pragma unroll
    for (int ks = 0; ks < 4; ++ks) {
        uint4 v = *reinterpret_cast<const uint4*>(part + (size_t)ks * (BL * E_) + base);
        const unsigned u[4] = {v.x, v.y, v.z, v.w};
#pragma unroll
        for (int j = 0; j < 4; ++j) {
            s[2 * j]     += bf2f(u[j] & 0xffffu);
            s[2 * j + 1] += bf2f(u[j] >> 16);
        }
    }
    *reinterpret_cast<float4*>(out + base)     = make_float4(s[0], s[1], s[2], s[3]);
    *reinterpret_cast<float4*>(out + base + 4) = make_float4(s[4], s[5], s[6], s[7]);
}

// ----------------------------------------------------------------
extern "C" void kernel_launch(void* const* d_in, const int* in_sizes, int n_in,
                              void* d_out, int out_size, void* d_ws, size_t ws_size,
                              hipStream_t stream) {
    const float* topk  = (const float*)d_in[0];
    const float* ts    = (const float*)d_in[1];
    const float* probs = (const float*)d_in[2];
    const float* qp    = (const float*)d_in[3];
    const float* kp    = (const float*)d_in[4];
    const float* vp    = (const float*)d_in[5];
    const float* ow    = (const float*)d_in[6];
    const float* ob    = (const float*)d_in[7];
    float* out = (float*)d_out;

    char* wp = (char*)d_ws;
    float* kk            = (float*)wp;           wp += 524288;
    float* vv            = (float*)wp;           wp += 524288;
    float* ab            = (float*)wp;           wp += 16384;
    unsigned short* tsb  = (unsigned short*)wp;  wp += 2097152;
    unsigned short* A2t  = (unsigned short*)wp;  wp += 2097152;
    unsigned short* VWt  = (unsigned short*)wp;  wp += (size_t)E_ * LDP * 2;   // 6,389,760
    unsigned short* P    = (unsigned short*)wp;  wp += (size_t)BL * LDP * 2;   // 34,078,720
    float* partk         = (float*)wp;           wp += 4194304;
    float* partv         = (float*)wp;           wp += 4194304;
    unsigned short* part = (unsigned short*)wp;  // 4 * 4096*768*2 = 25,165,824

    k1_kv <<<dim3(32, 8),  256, 0, stream>>>(topk, kp, vp, partk, partv);
    k1r0  <<<1664,         256, 0, stream>>>(partk, partv, kp, vp, kk, vv,
                                             ts, probs, ob, tsb, P, VWt);
    k23   <<<dim3(32, 8),  768, 0, stream>>>(qp, kk, ow, vv, A2t, ab, VWt);
    k4_att<<<dim3(32, 32), 256, 0, stream>>>(A2t, tsb, ab, probs, P);
    k5_out<<<1024,         256, 0, stream>>>(P, VWt, part);
    k6_red<<<1536,         256, 0, stream>>>(part, out);
}

// Round 8
// 117.873 us; speedup vs baseline: 1.1008x; 1.0395x over previous
//
#include <hip/hip_runtime.h>
#include <hip/hip_bf16.h>

#define C_   32
#define K_   16
#define DLLM 768
#define DM   256
#define H_   8
#define DK   32
#define G_   256
#define BL   4096
#define NN   4096
#define E_   768
#define LDP  4160          // P / VWt row stride: 4096 + 32 bias-fold + 32 zero pad
#define TEMPF 0.17677669529663687f
#define SCL2  0.2550348647f   // TEMP * log2(e)

typedef __attribute__((ext_vector_type(8))) short bf16x8;
typedef __attribute__((ext_vector_type(4))) float f32x4;
typedef unsigned int u32;

__device__ __forceinline__ unsigned short f2bf(float f) {
    unsigned int u = __float_as_uint(f);
    unsigned int r = (u + 0x7fffu + ((u >> 16) & 1u)) >> 16;
    return (unsigned short)r;
}
__device__ __forceinline__ float bf2f(unsigned int u) {
    return __uint_as_float(u << 16);
}

// async global -> LDS, 16 bytes per lane (wave-uniform LDS base + lane*16)
__device__ __forceinline__ void gl16(const void* g, void* l) {
    __builtin_amdgcn_global_load_lds(
        (const __attribute__((address_space(1))) u32*)g,
        (__attribute__((address_space(3))) u32*)l, 16, 0, 0);
}

// ---------------------------------------------------------------- K1: kk,v partial projections (d-split x8)
__global__ __launch_bounds__(256) void k1_kv(const float* __restrict__ topk,
                                             const float* __restrict__ kp,
                                             const float* __restrict__ vp,
                                             float* __restrict__ partk,
                                             float* __restrict__ partv) {
    const int c  = blockIdx.x;
    const int dc = blockIdx.y;
    const int d0 = dc * 96;
    const int g  = threadIdx.x;
    __shared__ float t_l[K_][96];
    for (int i = threadIdx.x; i < 384; i += 256) {
        int k = i / 24, c4 = (i % 24) * 4;
        *reinterpret_cast<float4*>(&t_l[k][c4]) =
            *reinterpret_cast<const float4*>(topk + (size_t)(c * K_ + k) * DLLM + d0 + c4);
    }
    __syncthreads();
    const float* kpr = kp + (size_t)(c * G_ + g) * (DLLM + 1) + d0;
    const float* vpr = vp + (size_t)(c * G_ + g) * (DLLM + 1) + d0;
    float acck[K_] = {}, accv[K_] = {};
    for (int d = 0; d < 96; d += 4) {
        float4 wk4 = *reinterpret_cast<const float4*>(kpr + d);
        float4 wv4 = *reinterpret_cast<const float4*>(vpr + d);
        const float wk[4] = {wk4.x, wk4.y, wk4.z, wk4.w};
        const float wv[4] = {wv4.x, wv4.y, wv4.z, wv4.w};
#pragma unroll
        for (int dd = 0; dd < 4; ++dd)
#pragma unroll
            for (int k = 0; k < K_; ++k) {
                acck[k] += wk[dd] * t_l[k][d + dd];
                accv[k] += wv[dd] * t_l[k][d + dd];
            }
    }
    float* pk = partk + ((size_t)(c * 8 + dc) * K_) * G_ + g;
    float* pv = partv + ((size_t)(c * 8 + dc) * K_) * G_ + g;
#pragma unroll
    for (int k = 0; k < K_; ++k) {
        pk[k * G_] = acck[k];
        pv[k * G_] = accv[k];
    }
}

// ---------------------------------------------------------------- K1r0: (merged) k1-reduce + cvt/bias-fold
__global__ __launch_bounds__(256) void k1r0(const float* __restrict__ partk,
                                            const float* __restrict__ partv,
                                            const float* __restrict__ kp,
                                            const float* __restrict__ vp,
                                            float* __restrict__ kk,
                                            float* __restrict__ vv,
                                            const float* __restrict__ ts,
                                            const float* __restrict__ probs,
                                            const float* __restrict__ outb,
                                            unsigned short* __restrict__ tsb,
                                            unsigned short* __restrict__ P,
                                            unsigned short* __restrict__ VWt) {
    const int bid0 = blockIdx.x, t = threadIdx.x;
    if (bid0 < 512) {                              // k1r: kk/vv = sum partials + bias
        const int idx = bid0 * 256 + t;
        const int g = idx & 255, rest = idx >> 8;
        const int k = rest & 15, c = rest >> 4;
        float sk = kp[(size_t)(c * G_ + g) * (DLLM + 1) + DLLM];
        float sv = vp[(size_t)(c * G_ + g) * (DLLM + 1) + DLLM];
#pragma unroll
        for (int dc = 0; dc < 8; ++dc) {
            sk += partk[((size_t)(c * 8 + dc) * K_ + k) * G_ + g];
            sv += partv[((size_t)(c * 8 + dc) * K_ + k) * G_ + g];
        }
        kk[idx] = sk;
        vv[idx] = sv;
        return;
    }
    const int bid = bid0 - 512;
    if (bid < 1024) {                              // ts (4096x256) -> bf16
        const int idx = bid * 1024 + t * 4;
        float4 v = *reinterpret_cast<const float4*>(ts + idx);
        uint2 o;
        o.x = f2bf(v.x) | ((unsigned)f2bf(v.y) << 16);
        o.y = f2bf(v.z) | ((unsigned)f2bf(v.w) << 16);
        *reinterpret_cast<uint2*>(tsb + idx) = o;
    } else if (bid < 1056) {                       // P[:,4096+c]=probs, P[:,4128..4159]=0
        const int b2 = bid - 1024;
        const int row = b2 * 128 + (t >> 1);
        const int ch = (t & 1) * 16;
        unsigned short o[16];
#pragma unroll
        for (int j = 0; j < 16; ++j) o[j] = f2bf(probs[row * 32 + ch + j]);
        uint4 u0, u1;
        u0.x = o[0] | (o[1] << 16);  u0.y = o[2] | (o[3] << 16);
        u0.z = o[4] | (o[5] << 16);  u0.w = o[6] | (o[7] << 16);
        u1.x = o[8] | (o[9] << 16);  u1.y = o[10] | (o[11] << 16);
        u1.z = o[12] | (o[13] << 16); u1.w = o[14] | (o[15] << 16);
        unsigned short* dst = P + (size_t)row * LDP + 4096 + ch;
        *reinterpret_cast<uint4*>(dst) = u0;
        *reinterpret_cast<uint4*>(dst + 8) = u1;
        uint4 z = {0u, 0u, 0u, 0u};
        unsigned short* pz = P + (size_t)row * LDP + 4128 + ch;
        *reinterpret_cast<uint4*>(pz) = z;
        *reinterpret_cast<uint4*>(pz + 8) = z;
    } else {                                       // VWt[e][4096+c]=outb[c][e]; pad=0
        const int idx = (bid - 1056) * 256 + t;    // 768*32 = 24576
        const int e = idx >> 5, cc = idx & 31;
        VWt[(size_t)e * LDP + 4096 + cc] = f2bf(outb[cc * E_ + e]);
        VWt[(size_t)e * LDP + 4128 + cc] = 0;
    }
}

// ---------------------------------------------------------------- K23: (merged) A2t + VWt builders
__global__ __launch_bounds__(768) void k23(const float* __restrict__ qp,
                                           const float* __restrict__ kk,
                                           const float* __restrict__ ow,
                                           const float* __restrict__ vv,
                                           unsigned short* __restrict__ A2t,
                                           float* __restrict__ abias,
                                           unsigned short* __restrict__ VWt) {
    const int c = blockIdx.x, h = blockIdx.y;
    const int t = threadIdx.x;
    __shared__ float kk_l[K_][DK];
    __shared__ float v_l[K_][DK];
    __shared__ float bq_l[DK];
    if (t < 512) {
        int k = t / DK, d = t % DK;
        kk_l[k][d] = kk[(size_t)(c * K_ + k) * G_ + h * DK + d];
        v_l[k][d]  = vv[(size_t)(c * K_ + k) * G_ + h * DK + d];
    }
    if (t < DK)
        bq_l[t] = qp[(size_t)(c * G_ + h * DK + t) * (DM + 1) + DM];
    __syncthreads();
    const int ch = c * H_ + h;
    {   // k3: VWt[e][n]
        const int e = t;
        float acc[K_];
#pragma unroll
        for (int k = 0; k < K_; ++k) acc[k] = 0.f;
        for (int d = 0; d < DK; ++d) {
            float w = ow[((size_t)ch * DK + d) * E_ + e];
#pragma unroll
            for (int k = 0; k < K_; ++k) acc[k] += w * v_l[k][d];
        }
#pragma unroll
        for (int k = 0; k < K_; ++k)
            VWt[(size_t)e * LDP + ch * 16 + k] = f2bf(acc[k]);
    }
    if (t < 256) {  // k2: A2t[n][m] (pre-scaled), abias
        const int m = t;
        float acc[K_];
#pragma unroll
        for (int k = 0; k < K_; ++k) acc[k] = 0.f;
        for (int d = 0; d < DK; ++d) {
            float wq = qp[(size_t)(c * G_ + h * DK + d) * (DM + 1) + m];
#pragma unroll
            for (int k = 0; k < K_; ++k) acc[k] += wq * kk_l[k][d];
        }
#pragma unroll
        for (int k = 0; k < K_; ++k)
            A2t[(size_t)(ch * 16 + k) * DM + m] = f2bf(acc[k] * SCL2);
        if (m < K_) {
            float s = 0.f;
#pragma unroll
            for (int d = 0; d < DK; ++d) s += bq_l[d] * kk_l[m][d];
            abias[ch * 16 + m] = s * SCL2;
        }
    }
}

// ---------------------------------------------------------------- K4: MFMA logits + exp2-softmax + prob scale -> P bf16
// BM(n)=128 x BN(bl)=256, BK=32; wave tile 64x128, acc[4][8]; gload_lds dbuf, conflict-free swizzle
__global__ __launch_bounds__(256, 2) void k4_att(const unsigned short* __restrict__ A2t,
                                                 const unsigned short* __restrict__ tsb,
                                                 const float* __restrict__ abias,
                                                 const float* __restrict__ probs,
                                                 unsigned short* __restrict__ P) {
    const int n0  = blockIdx.x * 128;
    const int bl0 = blockIdx.y * 256;
    const int t = threadIdx.x;
    const int lane = t & 63, w = t >> 6;
    const int wr = w >> 1, wc = w & 1;
    const int c = lane & 15, g = lane >> 4;
    const int rsl = (c >> 1) & 3;                  // reader chunk swizzle

    __shared__ unsigned short a_l[2][128 * 32];    // 8 KB / buf
    __shared__ unsigned short b_l[2][256 * 32];    // 16 KB / buf
    __shared__ float ab_l[128];
    __shared__ float pb_l[256];

    if (t < 128) ab_l[t] = abias[n0 + t];
    pb_l[t] = probs[(size_t)(bl0 + t) * C_ + (n0 >> 7)];

    // staging: 4 lanes/row; LDS dest linear; source chunk pre-swizzled by (row>>1)&3
    const int srow = t >> 2;                       // 0..63
    const int sw = ((t & 3) ^ ((t >> 3) & 3)) * 8;

    f32x4 acc[4][8] = {};

    // prologue: tile 0 -> buf 0
#pragma unroll
    for (int j = 0; j < 2; ++j)
        gl16(A2t + (size_t)(n0 + j * 64 + srow) * DM + sw, &a_l[0][j * 2048 + t * 8]);
#pragma unroll
    for (int j = 0; j < 4; ++j)
        gl16(tsb + (size_t)(bl0 + j * 64 + srow) * DM + sw, &b_l[0][j * 2048 + t * 8]);
    __syncthreads();

    for (int kt = 0; kt < 8; ++kt) {
        const int cur = kt & 1;
        if (kt < 7) {
            const int col = (kt + 1) * 32 + sw;
#pragma unroll
            for (int j = 0; j < 2; ++j)
                gl16(A2t + (size_t)(n0 + j * 64 + srow) * DM + col,
                     &a_l[cur ^ 1][j * 2048 + t * 8]);
#pragma unroll
            for (int j = 0; j < 4; ++j)
                gl16(tsb + (size_t)(bl0 + j * 64 + srow) * DM + col,
                     &b_l[cur ^ 1][j * 2048 + t * 8]);
        }
        bf16x8 af[4], bfr[8];
#pragma unroll
        for (int a = 0; a < 4; ++a)
            af[a] = *reinterpret_cast<const bf16x8*>(
                &a_l[cur][(wr * 64 + a * 16 + c) * 32 + (g ^ rsl) * 8]);
#pragma unroll
        for (int b = 0; b < 8; ++b)
            bfr[b] = *reinterpret_cast<const bf16x8*>(
                &b_l[cur][(wc * 128 + b * 16 + c) * 32 + (g ^ rsl) * 8]);
#pragma unroll
        for (int a = 0; a < 4; ++a)
#pragma unroll
            for (int b = 0; b < 8; ++b)
                acc[a][b] = __builtin_amdgcn_mfma_f32_16x16x32_bf16(af[a], bfr[b], acc[a][b], 0, 0, 0);
        __syncthreads();
    }

#pragma unroll
    for (int a = 0; a < 4; ++a) {
        const int nbase = wr * 64 + a * 16 + g * 4;
#pragma unroll
        for (int b = 0; b < 8; ++b) {
            const int bll = wc * 128 + b * 16 + c;
            float e0 = __builtin_amdgcn_exp2f(acc[a][b][0] + ab_l[nbase + 0]);
            float e1 = __builtin_amdgcn_exp2f(acc[a][b][1] + ab_l[nbase + 1]);
            float e2 = __builtin_amdgcn_exp2f(acc[a][b][2] + ab_l[nbase + 2]);
            float e3 = __builtin_amdgcn_exp2f(acc[a][b][3] + ab_l[nbase + 3]);
            float s = (e0 + e1) + (e2 + e3);
            s += __shfl_xor(s, 16);
            s += __shfl_xor(s, 32);
            const float pv = pb_l[bll] * __builtin_amdgcn_rcpf(s);
            unsigned r0, r1;
            float p0 = e0 * pv, p1 = e1 * pv, p2 = e2 * pv, p3 = e3 * pv;
            asm("v_cvt_pk_bf16_f32 %0, %1, %2" : "=v"(r0) : "v"(p0), "v"(p1));
            asm("v_cvt_pk_bf16_f32 %0, %1, %2" : "=v"(r1) : "v"(p2), "v"(p3));
            uint2 o; o.x = r0; o.y = r1;
            *reinterpret_cast<uint2*>(P + (size_t)(bl0 + bll) * LDP + n0 + nbase) = o;
        }
    }
}

// ---------------------------------------------------------------- K5: part[ks] = P(K-quarter) @ VWt^T  (bf16 partials)
// BM=128, BN=192, BK=32; wave tile 64x96, acc[4][6]; split-K=4; 512 blocks = 2/CU
__global__ __launch_bounds__(256, 2) void k5_out(const unsigned short* __restrict__ P,
                                                 const unsigned short* __restrict__ VWt,
                                                 unsigned short* __restrict__ part) {
    const int wg = blockIdx.x;                     // 0..511
    const int xcd = wg & 7;
    const int local = wg >> 3;                     // 0..63
    const int bl0 = (xcd * 4 + (local & 3)) * 128;
    const int e0  = ((local >> 2) & 3) * 192;
    const int ks  = local >> 4;                    // 0..3

    const int t = threadIdx.x;
    const int lane = t & 63, w = t >> 6;
    const int wr = w >> 1, wc = w & 1;
    const int c = lane & 15, g = lane >> 4;
    const int rsl = (c >> 1) & 3;

    __shared__ unsigned short a_l[2][128 * 32];    // 8 KB / buf
    __shared__ unsigned short b_l[2][192 * 32];    // 12 KB / buf

    const int nstart = ks * 1024;
    const int nsteps = (ks == 3) ? 34 : 32;

    // staging: 4 lanes/row, linear dest, source chunk swizzled by (row>>1)&3
    const int srow = t >> 2;                       // 0..63
    const int sw = ((t & 3) ^ ((t >> 3) & 3)) * 8;

    // prologue
#pragma unroll
    for (int j = 0; j < 2; ++j)
        gl16(P + (size_t)(bl0 + j * 64 + srow) * LDP + nstart + sw,
             &a_l[0][j * 2048 + t * 8]);
#pragma unroll
    for (int j = 0; j < 3; ++j)
        gl16(VWt + (size_t)(e0 + j * 64 + srow) * LDP + nstart + sw,
             &b_l[0][j * 2048 + t * 8]);
    __syncthreads();

    f32x4 acc[4][6] = {};
    for (int kt = 0; kt < nsteps; ++kt) {
        const int cur = kt & 1;
        if (kt + 1 < nsteps) {
            const int col = nstart + (kt + 1) * 32 + sw;
#pragma unroll
            for (int j = 0; j < 2; ++j)
                gl16(P + (size_t)(bl0 + j * 64 + srow) * LDP + col,
                     &a_l[cur ^ 1][j * 2048 + t * 8]);
#pragma unroll
            for (int j = 0; j < 3; ++j)
                gl16(VWt + (size_t)(e0 + j * 64 + srow) * LDP + col,
                     &b_l[cur ^ 1][j * 2048 + t * 8]);
        }
        bf16x8 af[4], bfr[6];
#pragma unroll
        for (int a = 0; a < 4; ++a)
            af[a] = *reinterpret_cast<const bf16x8*>(
                &a_l[cur][(wr * 64 + a * 16 + c) * 32 + (g ^ rsl) * 8]);
#pragma unroll
        for (int b = 0; b < 6; ++b)
            bfr[b] = *reinterpret_cast<const bf16x8*>(
                &b_l[cur][(wc * 96 + b * 16 + c) * 32 + (g ^ rsl) * 8]);
#pragma unroll
        for (int a = 0; a < 4; ++a)
#pragma unroll
            for (int b = 0; b < 6; ++b)
                acc[a][b] = __builtin_amdgcn_mfma_f32_16x16x32_bf16(af[a], bfr[b], acc[a][b], 0, 0, 0);
        __syncthreads();
    }

    unsigned short* pp = part + ((size_t)ks * BL + bl0) * E_ + e0;
#pragma unroll
    for (int a = 0; a < 4; ++a)
#pragma unroll
        for (int b = 0; b < 6; ++b)
#pragma unroll
            for (int i = 0; i < 4; ++i)
                pp[(size_t)(wr * 64 + a * 16 + g * 4 + i) * E_ + wc * 96 + b * 16 + c] =
                    f2bf(acc[a][b][i]);
}

// ---------------------------------------------------------------- k6: out = sum of 4 bf16 partials
__global__ __launch_bounds__(256) void k6_red(const unsigned short* __restrict__ part,
                                              float* __restrict__ out) {
    const size_t base = ((size_t)blockIdx.x * 256 + threadIdx.x) * 8;
    float s[8] = {};
#pragma unroll
    for (int ks = 0; ks < 4; ++ks) {
        uint4 v = *reinterpret_cast<const uint4*>(part + (size_t)ks * (BL * E_) + base);
        const unsigned u[4] = {v.x, v.y, v.z, v.w};
#pragma unroll
        for (int j = 0; j < 4; ++j) {
            s[2 * j]     += bf2f(u[j] & 0xffffu);
            s[2 * j + 1] += bf2f(u[j] >> 16);
        }
    }
    *reinterpret_cast<float4*>(out + base)     = make_float4(s[0], s[1], s[2], s[3]);
    *reinterpret_cast<float4*>(out + base + 4) = make_float4(s[4], s[5], s[6], s[7]);
}

// ----------------------------------------------------------------
extern "C" void kernel_launch(void* const* d_in, const int* in_sizes, int n_in,
                              void* d_out, int out_size, void* d_ws, size_t ws_size,
                              hipStream_t stream) {
    const float* topk  = (const float*)d_in[0];
    const float* ts    = (const float*)d_in[1];
    const float* probs = (const float*)d_in[2];
    const float* qp    = (const float*)d_in[3];
    const float* kp    = (const float*)d_in[4];
    const float* vp    = (const float*)d_in[5];
    const float* ow    = (const float*)d_in[6];
    const float* ob    = (const float*)d_in[7];
    float* out = (float*)d_out;

    char* wp = (char*)d_ws;
    float* kk            = (float*)wp;           wp += 524288;
    float* vv            = (float*)wp;           wp += 524288;
    float* ab            = (float*)wp;           wp += 16384;
    unsigned short* tsb  = (unsigned short*)wp;  wp += 2097152;
    unsigned short* A2t  = (unsigned short*)wp;  wp += 2097152;
    unsigned short* VWt  = (unsigned short*)wp;  wp += (size_t)E_ * LDP * 2;   // 6,389,760
    unsigned short* P    = (unsigned short*)wp;  wp += (size_t)BL * LDP * 2;   // 34,078,720
    float* partk         = (float*)wp;           wp += 4194304;
    float* partv         = (float*)wp;           wp += 4194304;
    unsigned short* part = (unsigned short*)wp;  // 4 * 4096*768*2 = 25,165,824

    k1_kv <<<dim3(32, 8),  256, 0, stream>>>(topk, kp, vp, partk, partv);
    k1r0  <<<1664,         256, 0, stream>>>(partk, partv, kp, vp, kk, vv,
                                             ts, probs, ob, tsb, P, VWt);
    k23   <<<dim3(32, 8),  768, 0, stream>>>(qp, kk, ow, vv, A2t, ab, VWt);
    k4_att<<<dim3(32, 16), 256, 0, stream>>>(A2t, tsb, ab, probs, P);
    k5_out<<<512,          256, 0, stream>>>(P, VWt, part);
    k6_red<<<1536,         256, 0, stream>>>(part, out);
}